// Round 1
// baseline (743.471 us; speedup 1.0000x reference)
//
#include <hip/hip_runtime.h>
#include <stdint.h>

typedef _Float16 f16;
typedef _Float16 f16x2 __attribute__((ext_vector_type(2)));
typedef _Float16 f16x4 __attribute__((ext_vector_type(4)));
typedef _Float16 f16x8 __attribute__((ext_vector_type(8)));
typedef float f32x4 __attribute__((ext_vector_type(4)));

#define AS1 __attribute__((address_space(1)))
#define AS3 __attribute__((address_space(3)))

// async global->LDS, 16B per lane; LDS dest = wave-uniform base + lane*16
__device__ __forceinline__ void gload_lds16(const f16* g, f16* l) {
    __builtin_amdgcn_global_load_lds((AS1 uint32_t*)g, (AS3 uint32_t*)l, 16, 0, 0);
}

__device__ __forceinline__ float fsig(float x) {
    return __builtin_amdgcn_rcpf(1.f + __builtin_amdgcn_exp2f(-1.44269504f * x));
}
__device__ __forceinline__ float ftanh(float x) {
    return 2.f * __builtin_amdgcn_rcpf(1.f + __builtin_amdgcn_exp2f(-2.88539008f * x)) - 1.f;
}
__device__ __forceinline__ float wave_sum(float v) {
#pragma unroll
    for (int off = 32; off >= 1; off >>= 1) v += __shfl_xor(v, off, 64);
    return v;
}

// ---------------- convert f32 -> f16 (x, h, W_i2h, W_h2h) ----------------
__global__ __launch_bounds__(256) void convert_kernel(
    const float* __restrict__ x, const float* __restrict__ h,
    const float* __restrict__ wi, const float* __restrict__ wh,
    f16* __restrict__ dst) {
    const int64_t NX = 16777216, NW = 4194304;
    int64_t g8 = ((int64_t)blockIdx.x * 256 + threadIdx.x) * 8;
    const float* src;
    int64_t off;
    if (g8 < NX)               { src = x;  off = g8; }
    else if (g8 < 2 * NX)      { src = h;  off = g8 - NX; }
    else if (g8 < 2 * NX + NW) { src = wi; off = g8 - 2 * NX; }
    else                       { src = wh; off = g8 - 2 * NX - NW; }
    f32x4 v0 = *(const f32x4*)(src + off);
    f32x4 v1 = *(const f32x4*)(src + off + 4);
    f16x8 o = { (f16)v0.x, (f16)v0.y, (f16)v0.z, (f16)v0.w,
                (f16)v1.x, (f16)v1.y, (f16)v1.z, (f16)v1.w };
    *(f16x8*)(dst + g8) = o;
}

// ---------------- GEMM: C[m][n] = sum_k A[m][k]*B[n][k], f16 in, f16 out ----
// 256x256 tile, BK=64, 8 waves (2Mx4N), 8-phase counted-vmcnt schedule.
// LDS [2buf][2khalf][256][32] f16, 128 KiB. Stage unit = one k-half of A or B
// (256x32, 2 gload_lds/wave). Steady state: vmcnt(8) at phases 2/4 of every
// K-tile, 8 loads always in flight; stages issued >=2 MFMA phases before use.
// Region lifetimes: buf[k0] dead after P2 -> restaged (t+2) at P3/P4;
// buf^1[k1] dead after previous tile's P4 -> staged (t+1) at P1/P2.
__global__ __launch_bounds__(512, 2) void gemm_8ph_f16(
    const f16* __restrict__ Abase, const f16* __restrict__ Bbase,
    f16* __restrict__ Cbase) {
    const int K = 1024, N = 4096;
    const int64_t M = 16384;
    const int z = blockIdx.z;
    const f16* A = Abase + (int64_t)z * M * K;
    const f16* B = Bbase + (int64_t)z * (int64_t)N * K;
    f16* C = Cbase + (int64_t)z * M * N;

    __shared__ f16 sA[2][2][256][32];
    __shared__ f16 sB[2][2][256][32];

    const int tid  = threadIdx.x;
    const int wave = tid >> 6;
    const int lane = tid & 63;
    const int q    = lane >> 4;
    const int l16  = lane & 15;
    const int wm   = (wave >> 2) * 128;   // 2 M-warps
    const int wn   = (wave & 3) * 64;     // 4 N-warps

    // XCD-aware chunked swizzle: 1024 wgs per z, 1024 % 8 == 0 -> bijective.
    const int wg  = blockIdx.y * 16 + blockIdx.x;
    const int swz = (wg & 7) * 128 + (wg >> 3);
    const int bm = (swz >> 4) * 256;
    const int bn = (swz & 15) * 256;

    const f16* Ab = A + (int64_t)bm * K;
    const f16* Bb = B + (int64_t)bn * K;

    // stage-side lane constants: row-in-16 and XOR-swizzled chunk offset (f16)
    const int srow = lane >> 2;
    const int sg   = ((lane & 3) ^ ((lane >> 3) & 3)) * 8;
    // read-side lane constant: swizzled chunk offset (f16)
    const int p8   = (q ^ ((l16 >> 1) & 3)) * 8;

    f32x4 acc[8][4];
#pragma unroll
    for (int i = 0; i < 8; ++i)
#pragma unroll
        for (int j = 0; j < 4; ++j) acc[i][j] = (f32x4){0.f, 0.f, 0.f, 0.f};

    f16x8 afr[4], bfr[4];

    auto STAGE = [&](const f16* __restrict__ gb, f16* plane, int kpos) {
#pragma unroll
        for (int i = 0; i < 2; ++i) {
            const int rowbase = i * 128 + wave * 16;
            gload_lds16(gb + (rowbase + srow) * 1024 + kpos + sg,
                        plane + rowbase * 32);
        }
    };
    auto LDA = [&](const f16* plane, int msub) {
#pragma unroll
        for (int i = 0; i < 4; ++i)
            afr[i] = *(const f16x8*)(plane + (wm + msub * 64 + i * 16 + l16) * 32 + p8);
    };
    auto LDB = [&](const f16* plane) {
#pragma unroll
        for (int i = 0; i < 4; ++i)
            bfr[i] = *(const f16x8*)(plane + (wn + i * 16 + l16) * 32 + p8);
    };
    // swapped operands: D-row(q*4+reg) = N-col, D-col(l16) = M-row -> 8B C stores
    auto MFMA = [&](int msub) {
        __builtin_amdgcn_s_setprio(1);
#pragma unroll
        for (int mi = 0; mi < 4; ++mi)
#pragma unroll
            for (int ni = 0; ni < 4; ++ni)
                acc[msub * 4 + mi][ni] = __builtin_amdgcn_mfma_f32_16x16x32_f16(
                    bfr[ni], afr[mi], acc[msub * 4 + mi][ni], 0, 0, 0);
        __builtin_amdgcn_s_setprio(0);
    };

    // prologue: SA0(0) SB0(0) SA1(0) SB1(0) SA0(1) SB0(1); wait k0(0) only
    STAGE(Ab, &sA[0][0][0][0], 0);
    STAGE(Bb, &sB[0][0][0][0], 0);
    STAGE(Ab, &sA[0][1][0][0], 32);
    STAGE(Bb, &sB[0][1][0][0], 32);
    STAGE(Ab, &sA[1][0][0][0], 64);
    STAGE(Bb, &sB[1][0][0][0], 64);
    asm volatile("s_waitcnt vmcnt(8)" ::: "memory");
    __builtin_amdgcn_s_barrier();

#pragma unroll 1
    for (int t = 0; t < 16; ++t) {
        const int buf = t & 1;
        const f16* A0 = &sA[buf][0][0][0];
        const f16* A1 = &sA[buf][1][0][0];
        const f16* B0 = &sB[buf][0][0][0];
        const f16* B1 = &sB[buf][1][0][0];

        // P1: (k0, m-sub0); stage SA1(t+1) -> other buf k1 (dead since P4(t-1))
        LDB(B0);
        LDA(A0, 0);
        if (t < 15) STAGE(Ab, &sA[buf ^ 1][1][0][0], (t + 1) * 64 + 32);
        __builtin_amdgcn_s_barrier();
        asm volatile("s_waitcnt lgkmcnt(0)" ::: "memory");
        __builtin_amdgcn_sched_barrier(0);
        MFMA(0);
        __builtin_amdgcn_s_barrier();

        // P2: (k0, m-sub1); stage SB1(t+1); wait k1(t) ready
        LDA(A0, 1);
        if (t < 15) STAGE(Bb, &sB[buf ^ 1][1][0][0], (t + 1) * 64 + 32);
        __builtin_amdgcn_s_barrier();
        asm volatile("s_waitcnt lgkmcnt(0)" ::: "memory");
        __builtin_amdgcn_sched_barrier(0);
        MFMA(1);
        if (t < 15) asm volatile("s_waitcnt vmcnt(8)" ::: "memory");
        else        asm volatile("s_waitcnt vmcnt(0)" ::: "memory");
        __builtin_amdgcn_s_barrier();

        // P3: (k1, m-sub0); stage SA0(t+2) -> this buf k0 (dead since P2(t))
        LDB(B1);
        LDA(A1, 0);
        if (t < 14) STAGE(Ab, &sA[buf][0][0][0], (t + 2) * 64);
        __builtin_amdgcn_s_barrier();
        asm volatile("s_waitcnt lgkmcnt(0)" ::: "memory");
        __builtin_amdgcn_sched_barrier(0);
        MFMA(0);
        __builtin_amdgcn_s_barrier();

        // P4: (k1, m-sub1); stage SB0(t+2); wait k0(t+1) ready
        LDA(A1, 1);
        if (t < 14) STAGE(Bb, &sB[buf][0][0][0], (t + 2) * 64);
        __builtin_amdgcn_s_barrier();
        asm volatile("s_waitcnt lgkmcnt(0)" ::: "memory");
        __builtin_amdgcn_sched_barrier(0);
        MFMA(1);
        if (t < 14)       asm volatile("s_waitcnt vmcnt(8)" ::: "memory");
        else if (t == 14) asm volatile("s_waitcnt vmcnt(4)" ::: "memory");
        __builtin_amdgcn_s_barrier();
    }

    // epilogue: lane holds 4 consecutive cols per frag -> 8B stores
#pragma unroll
    for (int mt = 0; mt < 8; ++mt) {
        const int row = bm + wm + mt * 16 + l16;
        f16* crow = C + (int64_t)row * N + bn + wn + q * 4;
#pragma unroll
        for (int nt = 0; nt < 4; ++nt) {
            f16x4 v = { (f16)acc[mt][nt][0], (f16)acc[mt][nt][1],
                        (f16)acc[mt][nt][2], (f16)acc[mt][nt][3] };
            *(f16x4*)(crow + nt * 16) = v;
        }
    }
}

// ---------------- fused LN + LSTM gates + LN(c_new) ----------------
__global__ __launch_bounds__(256) void lstm_fuse(
    const f16* __restrict__ i2h, const f16* __restrict__ h2h,
    const float* __restrict__ c,
    const float* __restrict__ gi, const float* __restrict__ bi,
    const float* __restrict__ gh, const float* __restrict__ bh,
    const float* __restrict__ gc, const float* __restrict__ bc,
    const float* __restrict__ bias,
    float* __restrict__ hout, float* __restrict__ cout) {
    const int tid  = threadIdx.x;
    const int row  = blockIdx.x * 2 + (tid >> 7);
    const int t    = tid & 127;
    const int wave = tid >> 6;
    const int lane = tid & 63;
    const int j0   = t * 8;

    const f16* pi = i2h + (int64_t)row * 4096;
    const f16* ph = h2h + (int64_t)row * 4096;

    f16x8 av[4], bv[4];
#pragma unroll
    for (int q = 0; q < 4; q++) {
        av[q] = *(const f16x8*)(pi + q * 1024 + j0);
        bv[q] = *(const f16x8*)(ph + q * 1024 + j0);
    }

    const f16x2 ones = { (f16)1.f, (f16)1.f };
    float si = 0.f, ssi = 0.f, sh = 0.f, ssh = 0.f;
#pragma unroll
    for (int q = 0; q < 4; q++) {
#pragma unroll
        for (int p = 0; p < 4; p++) {
            f16x2 a2 = { av[q][2 * p], av[q][2 * p + 1] };
            f16x2 b2 = { bv[q][2 * p], bv[q][2 * p + 1] };
            si  = __builtin_amdgcn_fdot2(a2, ones, si, false);
            ssi = __builtin_amdgcn_fdot2(a2, a2, ssi, false);
            sh  = __builtin_amdgcn_fdot2(b2, ones, sh, false);
            ssh = __builtin_amdgcn_fdot2(b2, b2, ssh, false);
        }
    }

    __shared__ float red[4][4];
    si = wave_sum(si); ssi = wave_sum(ssi); sh = wave_sum(sh); ssh = wave_sum(ssh);
    if (lane == 0) { red[wave][0] = si; red[wave][1] = ssi; red[wave][2] = sh; red[wave][3] = ssh; }
    __syncthreads();
    const int wb = wave & 2;
    si  = red[wb][0] + red[wb + 1][0];
    ssi = red[wb][1] + red[wb + 1][1];
    sh  = red[wb][2] + red[wb + 1][2];
    ssh = red[wb][3] + red[wb + 1][3];

    const float inv4096 = 1.0f / 4096.0f;
    float mi  = si * inv4096;
    float rsi = __builtin_amdgcn_rsqf(ssi * inv4096 - mi * mi + 1e-5f);
    float mh  = sh * inv4096;
    float rsh = __builtin_amdgcn_rsqf(ssh * inv4096 - mh * mh + 1e-5f);

    float lgf[8], lgi_[8], lgo[8], lgg[8];
    float* lgq[4] = { lgf, lgi_, lgo, lgg };
#pragma unroll
    for (int q = 0; q < 4; q++) {
#pragma unroll
        for (int g4 = 0; g4 < 2; g4++) {
            int jj = q * 1024 + j0 + g4 * 4;
            f32x4 giv = *(const f32x4*)(gi + jj);
            f32x4 biv = *(const f32x4*)(bi + jj);
            f32x4 ghv = *(const f32x4*)(gh + jj);
            f32x4 bhv = *(const f32x4*)(bh + jj);
            f32x4 bbv = *(const f32x4*)(bias + jj);
#pragma unroll
            for (int u = 0; u < 4; u++) {
                float t1 = rsi * giv[u];
                float t2 = rsh * ghv[u];
                float base = biv[u] + bhv[u] + bbv[u] - mi * t1 - mh * t2;
                lgq[q][g4 * 4 + u] =
                    (float)av[q][g4 * 4 + u] * t1 + (float)bv[q][g4 * 4 + u] * t2 + base;
            }
        }
    }

    f32x4 cv0 = *(const f32x4*)(c + (int64_t)row * 1024 + j0);
    f32x4 cv1 = *(const f32x4*)(c + (int64_t)row * 1024 + j0 + 4);
    float cn[8];
    float sc = 0.f, ssc = 0.f;
#pragma unroll
    for (int u = 0; u < 8; u++) {
        float cvu = (u < 4) ? cv0[u & 3] : cv1[u & 3];
        float fg = fsig(lgf[u]);
        float ig = fsig(lgi_[u]);
        float gg = ftanh(lgg[u]);
        float v = fg * cvu + ig * gg;
        cn[u] = v; sc += v; ssc += v * v;
    }

    __shared__ float red2[4][2];
    sc = wave_sum(sc); ssc = wave_sum(ssc);
    if (lane == 0) { red2[wave][0] = sc; red2[wave][1] = ssc; }
    __syncthreads();
    sc  = red2[wb][0] + red2[wb + 1][0];
    ssc = red2[wb][1] + red2[wb + 1][1];

    const float inv1024 = 1.0f / 1024.0f;
    float mc  = sc * inv1024;
    float rsc = __builtin_amdgcn_rsqf(ssc * inv1024 - mc * mc + 1e-5f);

    f32x4 gc0 = *(const f32x4*)(gc + j0);
    f32x4 gc1 = *(const f32x4*)(gc + j0 + 4);
    f32x4 bc0 = *(const f32x4*)(bc + j0);
    f32x4 bc1 = *(const f32x4*)(bc + j0 + 4);
    f32x4 h0, h1, c0, c1;
#pragma unroll
    for (int u = 0; u < 8; u++) {
        float gcv = (u < 4) ? gc0[u & 3] : gc1[u & 3];
        float bcv = (u < 4) ? bc0[u & 3] : bc1[u & 3];
        float og  = fsig(lgo[u]);
        float lnc = (cn[u] - mc) * rsc * gcv + bcv;
        float hv  = og * ftanh(lnc);
        if (u < 4) { h0[u & 3] = hv; c0[u & 3] = cn[u]; }
        else       { h1[u & 3] = hv; c1[u & 3] = cn[u]; }
    }
    float* hp = hout + (int64_t)row * 1024 + j0;
    float* cp = cout + (int64_t)row * 1024 + j0;
    *(f32x4*)hp       = h0;
    *(f32x4*)(hp + 4) = h1;
    *(f32x4*)cp       = c0;
    *(f32x4*)(cp + 4) = c1;
}

extern "C" void kernel_launch(void* const* d_in, const int* in_sizes, int n_in,
                              void* d_out, int out_size, void* d_ws, size_t ws_size,
                              hipStream_t stream) {
    const float* x      = (const float*)d_in[0];
    const float* h      = (const float*)d_in[1];
    const float* c      = (const float*)d_in[2];
    const float* wi     = (const float*)d_in[3];
    const float* wh     = (const float*)d_in[4];
    const float* ln_i_g = (const float*)d_in[5];
    const float* ln_i_b = (const float*)d_in[6];
    const float* ln_h_g = (const float*)d_in[7];
    const float* ln_h_b = (const float*)d_in[8];
    const float* ln_c_g = (const float*)d_in[9];
    const float* ln_c_b = (const float*)d_in[10];
    const float* bias   = (const float*)d_in[11];

    // ws layout (f16 elements):
    //   xh16    @ 0         : 2 * 16777216   (x then h)
    //   w16     @ 33554432  : 2 * 4194304    (W_i2h then W_h2h)
    //   logits16@ 41943040  : 2 * 67108864   (i2h then h2h)
    f16* ws16     = (f16*)d_ws;
    f16* xh16     = ws16;
    f16* w16      = ws16 + 33554432;
    f16* logits16 = ws16 + 41943040;

    convert_kernel<<<20480, 256, 0, stream>>>(x, h, wi, wh, ws16);
    gemm_8ph_f16<<<dim3(16, 64, 2), 512, 0, stream>>>(xh16, w16, logits16);

    float* hout = (float*)d_out;
    float* cout = hout + 16777216;
    lstm_fuse<<<8192, 256, 0, stream>>>(logits16, logits16 + 67108864, c,
                                        ln_i_g, ln_i_b, ln_h_g, ln_h_b,
                                        ln_c_g, ln_c_b, bias, hout, cout);
}

// Round 2
// 669.433 us; speedup vs baseline: 1.1106x; 1.1106x over previous
//
#include <hip/hip_runtime.h>
#include <stdint.h>

typedef _Float16 f16;
typedef _Float16 f16x2 __attribute__((ext_vector_type(2)));
typedef _Float16 f16x4 __attribute__((ext_vector_type(4)));
typedef _Float16 f16x8 __attribute__((ext_vector_type(8)));
typedef float f32x4 __attribute__((ext_vector_type(4)));

#define AS1 __attribute__((address_space(1)))
#define AS3 __attribute__((address_space(3)))

// async global->LDS, 16B per lane; LDS dest = wave-uniform base + lane*16
__device__ __forceinline__ void gload_lds16(const f16* g, f16* l) {
    __builtin_amdgcn_global_load_lds((AS1 uint32_t*)g, (AS3 uint32_t*)l, 16, 0, 0);
}

__device__ __forceinline__ float fsig(float x) {
    return __builtin_amdgcn_rcpf(1.f + __builtin_amdgcn_exp2f(-1.44269504f * x));
}
__device__ __forceinline__ float ftanh(float x) {
    return 2.f * __builtin_amdgcn_rcpf(1.f + __builtin_amdgcn_exp2f(-2.88539008f * x)) - 1.f;
}
__device__ __forceinline__ float wave_sum(float v) {
#pragma unroll
    for (int off = 32; off >= 1; off >>= 1) v += __shfl_xor(v, off, 64);
    return v;
}

// ---------------- convert f32 -> f16 (x, h, W_i2h, W_h2h) ----------------
__global__ __launch_bounds__(256) void convert_kernel(
    const float* __restrict__ x, const float* __restrict__ h,
    const float* __restrict__ wi, const float* __restrict__ wh,
    f16* __restrict__ dst) {
    const int64_t NX = 16777216, NW = 4194304;
    int64_t g8 = ((int64_t)blockIdx.x * 256 + threadIdx.x) * 8;
    const float* src;
    int64_t off;
    if (g8 < NX)               { src = x;  off = g8; }
    else if (g8 < 2 * NX)      { src = h;  off = g8 - NX; }
    else if (g8 < 2 * NX + NW) { src = wi; off = g8 - 2 * NX; }
    else                       { src = wh; off = g8 - 2 * NX - NW; }
    f32x4 v0 = *(const f32x4*)(src + off);
    f32x4 v1 = *(const f32x4*)(src + off + 4);
    f16x8 o = { (f16)v0.x, (f16)v0.y, (f16)v0.z, (f16)v0.w,
                (f16)v1.x, (f16)v1.y, (f16)v1.z, (f16)v1.w };
    *(f16x8*)(dst + g8) = o;
}

// ---------------- GEMM: C[m][n] = sum_k A[m][k]*B[n][k], f16 in, f16 out ----------------
// Proven R0 kernel: 128x128 tile, BK=64, XOR-swizzled LDS, global_load_lds w=16,
// ~971 TF measured, 0 LDS bank conflicts, 3 blocks/CU.
__global__ __launch_bounds__(256, 2) void gemm_bt_f16(
    const f16* __restrict__ Abase, const f16* __restrict__ Bbase,
    f16* __restrict__ Cbase) {
    const int K = 1024, N = 4096, M = 16384;
    const int z = blockIdx.z;
    const f16* A = Abase + (int64_t)z * M * K;
    const f16* B = Bbase + (int64_t)z * N * K;
    f16* C = Cbase + (int64_t)z * (int64_t)M * N;

    __shared__ f16 sA[128 * 64];
    __shared__ f16 sB[128 * 64];

    const int tid = threadIdx.x;
    const int wave = tid >> 6;
    const int lane = tid & 63;
    const int wm = (wave >> 1) * 64;
    const int wn = (wave & 1) * 64;
    const int bm = blockIdx.y * 128;
    const int bn = blockIdx.x * 128;

    const int srow = lane >> 3;
    const int sp   = lane & 7;

    const int quad = lane >> 4;
    const int l16  = lane & 15;

    f32x4 acc[4][4];
#pragma unroll
    for (int i = 0; i < 4; i++)
#pragma unroll
        for (int j = 0; j < 4; j++) acc[i][j] = (f32x4){0.f, 0.f, 0.f, 0.f};

    for (int k0 = 0; k0 < K; k0 += 64) {
#pragma unroll
        for (int i = 0; i < 4; i++) {
            int rowbase = wave * 32 + i * 8;
            int r = rowbase + srow;
            int c = sp ^ (r & 7);
            gload_lds16(A + (int64_t)(bm + r) * K + (k0 + c * 8), &sA[rowbase * 64]);
            gload_lds16(B + (int64_t)(bn + r) * K + (k0 + c * 8), &sB[rowbase * 64]);
        }
        __syncthreads();

#pragma unroll
        for (int ks = 0; ks < 2; ks++) {
            f16x8 a[4], b[4];
#pragma unroll
            for (int mt = 0; mt < 4; mt++) {
                int r = wm + mt * 16 + l16;
                int pp = (ks * 4 + quad) ^ (r & 7);
                a[mt] = *(const f16x8*)&sA[r * 64 + pp * 8];
            }
#pragma unroll
            for (int nt = 0; nt < 4; nt++) {
                int r = wn + nt * 16 + l16;
                int pp = (ks * 4 + quad) ^ (r & 7);
                b[nt] = *(const f16x8*)&sB[r * 64 + pp * 8];
            }
#pragma unroll
            for (int mt = 0; mt < 4; mt++)
#pragma unroll
                for (int nt = 0; nt < 4; nt++)
                    acc[mt][nt] = __builtin_amdgcn_mfma_f32_16x16x32_f16(
                        a[mt], b[nt], acc[mt][nt], 0, 0, 0);
        }
        __syncthreads();
    }

#pragma unroll
    for (int mt = 0; mt < 4; mt++) {
#pragma unroll
        for (int nt = 0; nt < 4; nt++) {
#pragma unroll
            for (int r = 0; r < 4; r++) {
                int row = bm + wm + mt * 16 + quad * 4 + r;
                int col = bn + wn + nt * 16 + l16;
                C[(int64_t)row * N + col] = (f16)acc[mt][nt][r];
            }
        }
    }
}

// ---------------- fused LN + LSTM gates + LN(c_new) ----------------
// 2 rows/block; 128 threads (2 waves) per row; 8 c-elems/thread.
// lg[4][8] indexed ONLY by compile-time-constant unroll vars — no pointer
// array, no address-taken locals -> stays in registers (no scratch).
__global__ __launch_bounds__(256) void lstm_fuse(
    const f16* __restrict__ i2h, const f16* __restrict__ h2h,
    const float* __restrict__ c,
    const float* __restrict__ gi, const float* __restrict__ bi,
    const float* __restrict__ gh, const float* __restrict__ bh,
    const float* __restrict__ gc, const float* __restrict__ bc,
    const float* __restrict__ bias,
    float* __restrict__ hout, float* __restrict__ cout) {
    const int tid  = threadIdx.x;
    const int row  = blockIdx.x * 2 + (tid >> 7);
    const int t    = tid & 127;
    const int wave = tid >> 6;     // 0..3; waves {0,1} = row A, {2,3} = row B
    const int lane = tid & 63;
    const int j0   = t * 8;

    const f16* pi = i2h + (int64_t)row * 4096;
    const f16* ph = h2h + (int64_t)row * 4096;

    f16x8 av[4], bv[4];
#pragma unroll
    for (int q = 0; q < 4; q++) {
        av[q] = *(const f16x8*)(pi + q * 1024 + j0);
        bv[q] = *(const f16x8*)(ph + q * 1024 + j0);
    }

    const f16x2 ones = { (f16)1.f, (f16)1.f };
    float si = 0.f, ssi = 0.f, sh = 0.f, ssh = 0.f;
#pragma unroll
    for (int q = 0; q < 4; q++) {
#pragma unroll
        for (int p = 0; p < 4; p++) {
            f16x2 a2 = { av[q][2 * p], av[q][2 * p + 1] };
            f16x2 b2 = { bv[q][2 * p], bv[q][2 * p + 1] };
            si  = __builtin_amdgcn_fdot2(a2, ones, si, false);
            ssi = __builtin_amdgcn_fdot2(a2, a2, ssi, false);
            sh  = __builtin_amdgcn_fdot2(b2, ones, sh, false);
            ssh = __builtin_amdgcn_fdot2(b2, b2, ssh, false);
        }
    }

    __shared__ float red[4][4];
    si = wave_sum(si); ssi = wave_sum(ssi); sh = wave_sum(sh); ssh = wave_sum(ssh);
    if (lane == 0) { red[wave][0] = si; red[wave][1] = ssi; red[wave][2] = sh; red[wave][3] = ssh; }
    __syncthreads();
    const int wb = wave & 2;
    si  = red[wb][0] + red[wb + 1][0];
    ssi = red[wb][1] + red[wb + 1][1];
    sh  = red[wb][2] + red[wb + 1][2];
    ssh = red[wb][3] + red[wb + 1][3];

    const float inv4096 = 1.0f / 4096.0f;
    float mi  = si * inv4096;
    float rsi = __builtin_amdgcn_rsqf(ssi * inv4096 - mi * mi + 1e-5f);
    float mh  = sh * inv4096;
    float rsh = __builtin_amdgcn_rsqf(ssh * inv4096 - mh * mh + 1e-5f);

    // combined logits for the 4 gates, 8 elems each; constant indices only
    float lg[4][8];
#pragma unroll
    for (int q = 0; q < 4; q++) {
#pragma unroll
        for (int g4 = 0; g4 < 2; g4++) {
            int jj = q * 1024 + j0 + g4 * 4;
            f32x4 giv = *(const f32x4*)(gi + jj);
            f32x4 biv = *(const f32x4*)(bi + jj);
            f32x4 ghv = *(const f32x4*)(gh + jj);
            f32x4 bhv = *(const f32x4*)(bh + jj);
            f32x4 bbv = *(const f32x4*)(bias + jj);
#pragma unroll
            for (int u = 0; u < 4; u++) {
                float t1 = rsi * giv[u];
                float t2 = rsh * ghv[u];
                float base = biv[u] + bhv[u] + bbv[u] - mi * t1 - mh * t2;
                lg[q][g4 * 4 + u] =
                    (float)av[q][g4 * 4 + u] * t1 + (float)bv[q][g4 * 4 + u] * t2 + base;
            }
        }
    }

    f32x4 cv0 = *(const f32x4*)(c + (int64_t)row * 1024 + j0);
    f32x4 cv1 = *(const f32x4*)(c + (int64_t)row * 1024 + j0 + 4);
    float cn[8];
    float sc = 0.f, ssc = 0.f;
#pragma unroll
    for (int u = 0; u < 8; u++) {
        float cvu = (u < 4) ? cv0[u & 3] : cv1[u & 3];
        float fg = fsig(lg[0][u]);
        float ig = fsig(lg[1][u]);
        float gg = ftanh(lg[3][u]);
        float v = fg * cvu + ig * gg;
        cn[u] = v; sc += v; ssc += v * v;
    }

    __shared__ float red2[4][2];
    sc = wave_sum(sc); ssc = wave_sum(ssc);
    if (lane == 0) { red2[wave][0] = sc; red2[wave][1] = ssc; }
    __syncthreads();
    sc  = red2[wb][0] + red2[wb + 1][0];
    ssc = red2[wb][1] + red2[wb + 1][1];

    const float inv1024 = 1.0f / 1024.0f;
    float mc  = sc * inv1024;
    float rsc = __builtin_amdgcn_rsqf(ssc * inv1024 - mc * mc + 1e-5f);

    f32x4 gc0 = *(const f32x4*)(gc + j0);
    f32x4 gc1 = *(const f32x4*)(gc + j0 + 4);
    f32x4 bc0 = *(const f32x4*)(bc + j0);
    f32x4 bc1 = *(const f32x4*)(bc + j0 + 4);
    f32x4 h0, h1, c0, c1;
#pragma unroll
    for (int u = 0; u < 8; u++) {
        float gcv = (u < 4) ? gc0[u & 3] : gc1[u & 3];
        float bcv = (u < 4) ? bc0[u & 3] : bc1[u & 3];
        float og  = fsig(lg[2][u]);
        float lnc = (cn[u] - mc) * rsc * gcv + bcv;
        float hv  = og * ftanh(lnc);
        if (u < 4) { h0[u & 3] = hv; c0[u & 3] = cn[u]; }
        else       { h1[u & 3] = hv; c1[u & 3] = cn[u]; }
    }
    float* hp = hout + (int64_t)row * 1024 + j0;
    float* cp = cout + (int64_t)row * 1024 + j0;
    *(f32x4*)hp       = h0;
    *(f32x4*)(hp + 4) = h1;
    *(f32x4*)cp       = c0;
    *(f32x4*)(cp + 4) = c1;
}

extern "C" void kernel_launch(void* const* d_in, const int* in_sizes, int n_in,
                              void* d_out, int out_size, void* d_ws, size_t ws_size,
                              hipStream_t stream) {
    const float* x      = (const float*)d_in[0];
    const float* h      = (const float*)d_in[1];
    const float* c      = (const float*)d_in[2];
    const float* wi     = (const float*)d_in[3];
    const float* wh     = (const float*)d_in[4];
    const float* ln_i_g = (const float*)d_in[5];
    const float* ln_i_b = (const float*)d_in[6];
    const float* ln_h_g = (const float*)d_in[7];
    const float* ln_h_b = (const float*)d_in[8];
    const float* ln_c_g = (const float*)d_in[9];
    const float* ln_c_b = (const float*)d_in[10];
    const float* bias   = (const float*)d_in[11];

    // ws layout (f16 elements):
    //   xh16    @ 0         : 2 * 16777216   (x then h)
    //   w16     @ 33554432  : 2 * 4194304    (W_i2h then W_h2h)
    //   logits16@ 41943040  : 2 * 67108864   (i2h then h2h)
    f16* ws16     = (f16*)d_ws;
    f16* xh16     = ws16;
    f16* w16      = ws16 + 33554432;
    f16* logits16 = ws16 + 41943040;

    convert_kernel<<<20480, 256, 0, stream>>>(x, h, wi, wh, ws16);
    gemm_bt_f16<<<dim3(32, 128, 2), 256, 0, stream>>>(xh16, w16, logits16);

    float* hout = (float*)d_out;
    float* cout = hout + 16777216;
    lstm_fuse<<<8192, 256, 0, stream>>>(logits16, logits16 + 67108864, c,
                                        ln_i_g, ln_i_b, ln_h_g, ln_h_b,
                                        ln_c_g, ln_c_b, bias, hout, cout);
}